// Round 2
// baseline (1301.847 us; speedup 1.0000x reference)
//
#include <hip/hip_runtime.h>
#include <hip/hip_bf16.h>
#include <stdint.h>

// Problem constants
#define TOKENS 4096
#define DM     512
#define VOCAB  128000
#define BN     128                 // vocab rows per block (resident in LDS)
#define BMT    512                 // token tile (8 token-groups x 64 tokens)
#define NCHUNK (VOCAB / BN)        // 1000
#define NTILE  (TOKENS / BMT)      // 8

// ws layout (needs ~20.6 MB)
#define XBF_OFF  0
#define PART_OFF (TOKENS * DM * 2)                       // 4,194,304
#define T_OFF    (PART_OFF + NCHUNK * TOKENS * 4)        // +16,384,000
#define LDS_BYTES (BN * DM * 2 + BMT * 2 * 4)            // 131072 + 4096 = 135168

typedef __attribute__((ext_vector_type(8))) short short8;
typedef __attribute__((ext_vector_type(4))) float f32x4;

__device__ __forceinline__ unsigned short f2bf(float f) {
  unsigned u;
  __builtin_memcpy(&u, &f, 4);
  u += 0x7fffu + ((u >> 16) & 1u);        // round-to-nearest-even
  return (unsigned short)(u >> 16);
}

// ---------------- stage 0: x fp32 -> bf16, zero the output scalar ----------
__global__ void cvt_x_kernel(const float* __restrict__ x,
                             unsigned short* __restrict__ xb,
                             float* __restrict__ out) {
  int i = (blockIdx.x * 256 + threadIdx.x) * 4;   // 2048 blocks * 256 * 4 = 2,097,152
  float4 v = *(const float4*)(x + i);
  ushort4 o;
  o.x = f2bf(v.x); o.y = f2bf(v.y); o.z = f2bf(v.z); o.w = f2bf(v.w);
  *(ushort4*)(xb + i) = o;
  if (blockIdx.x == 0 && threadIdx.x == 0) out[0] = 0.0f;
}

// ---------------- stage 1: W-chunk-resident GEMM + per-chunk sumexp --------
// Block c: W rows [c*128, c*128+128) resident in LDS (bf16) in FRAGMENT-LINEAR
// layout [R:8][S:16][q:4][slot:16] (16B short8 units); A-fragment read for
// K-slice s is Wl[R*1024 + s*64 + (lane ^ (s&7))] -- uniform-XOR permutation
// of 64 contiguous 16B slots (conflict-free; identical to verified R1 layout).
// 1024 threads = 16 waves = 2 row-groups x 8 token-groups; each wave owns
// 64 vocab rows x 64 tokens (r=4, c=4), acc = 64 AGPR, single-buffered B
// (4 waves/SIMD provide the latency hiding). X (B-operand) loaded directly
// from global (L2-resident bf16). Row-group partials combined via 4 KB LDS.
__global__ __launch_bounds__(1024, 4) void gemm_sumexp_kernel(
    const float* __restrict__ W, const unsigned short* __restrict__ Xb,
    float* __restrict__ part) {
  extern __shared__ char smem[];
  short8* Wl = (short8*)smem;                     // 8192 x 16B = 128 KB
  float*  sc = (float*)(smem + BN * DM * 2);      // [2][512] row-group partials

  const int tid  = threadIdx.x;
  const int c    = blockIdx.x;
  const int lane = tid & 63;
  const int w    = tid >> 6;        // wave 0..15
  const int tg   = w & 7;           // token group (64 tokens)
  const int rg   = w >> 3;          // row group (64 vocab rows)
  const int ln   = lane & 15;
  const int quad = lane >> 4;

  // ---- load W chunk fp32 -> bf16 -> LDS (fragment-linear; once per block)
  {
    const float* Wg = W + (size_t)c * BN * DM;
    #pragma unroll
    for (int it = 0; it < 8; ++it) {
      int b  = it * 1024 + tid;               // 0..8191 16B-blocks
      int n  = b >> 6;                        // W row 0..127
      int kb = b & 63;                        // 16B block within row
      const f32x4* p = (const f32x4*)(Wg + n * DM + kb * 8);
      f32x4 v0 = __builtin_nontemporal_load(p);      // W is streamed: keep L2 for X
      f32x4 v1 = __builtin_nontemporal_load(p + 1);
      short8 s;
      s[0] = (short)f2bf(v0[0]); s[1] = (short)f2bf(v0[1]);
      s[2] = (short)f2bf(v0[2]); s[3] = (short)f2bf(v0[3]);
      s[4] = (short)f2bf(v1[0]); s[5] = (short)f2bf(v1[1]);
      s[6] = (short)f2bf(v1[2]); s[7] = (short)f2bf(v1[3]);
      int S = kb >> 2, q = kb & 3;
      Wl[(n >> 4) * 1024 + S * 64 + q * 16 + ((n & 15) ^ (S & 7))] = s;
    }
  }
  __syncthreads();

  #pragma unroll 1
  for (int t = 0; t < NTILE; ++t) {
    f32x4 acc[4][4];
    #pragma unroll
    for (int i = 0; i < 4; ++i)
      #pragma unroll
      for (int j = 0; j < 4; ++j)
        acc[i][j] = f32x4{0.f, 0.f, 0.f, 0.f};

    // B-fragment base: lane holds token (t*512 + tg*64 + j*16 + ln),
    // k-elements quad*8..quad*8+7 within each K=32 slice s.
    const unsigned short* xrow =
        Xb + (size_t)(t * BMT + tg * 64 + ln) * DM + quad * 8;

    #pragma unroll 1
    for (int s = 0; s < DM / 32; ++s) {
      short8 bf[4], af[4];
      #pragma unroll
      for (int j = 0; j < 4; ++j)
        bf[j] = *(const short8*)(xrow + j * 16 * DM + s * 32);
      const int rb = s * 64 + (lane ^ (s & 7));
      #pragma unroll
      for (int i = 0; i < 4; ++i)
        af[i] = Wl[(rg * 4 + i) * 1024 + rb];
      __builtin_amdgcn_s_setprio(1);
      #pragma unroll
      for (int i = 0; i < 4; ++i)
        #pragma unroll
        for (int j = 0; j < 4; ++j)
          acc[i][j] = __builtin_amdgcn_mfma_f32_16x16x32_bf16(
              af[i], bf[j], acc[i][j], 0, 0, 0);
      __builtin_amdgcn_s_setprio(0);
    }

    // epilogue: acc[i][j][r] -> token = tg*64 + j*16 + ln (col = lane&15),
    // vocab row = rg*64 + i*16 + quad*4 + r. Sum exp per lane over this
    // wave's 64 rows, fold quads via shfl, combine row-groups through LDS.
    float ev[4];
    #pragma unroll
    for (int j = 0; j < 4; ++j) {
      float e = 0.f;
      #pragma unroll
      for (int i = 0; i < 4; ++i) {
        #pragma unroll
        for (int r = 0; r < 4; ++r) e += __expf(acc[i][j][r]);
      }
      e += __shfl_xor(e, 16, 64);
      e += __shfl_xor(e, 32, 64);
      ev[j] = e;
    }
    __syncthreads();                 // previous tile's sc fully consumed
    #pragma unroll
    for (int j = 0; j < 4; ++j)
      if (lane < 16) sc[rg * 512 + tg * 64 + j * 16 + lane] = ev[j];
    __syncthreads();
    if (tid < 512) {
      float v = sc[tid] + sc[512 + tid];
      float* pp = part + (size_t)c * TOKENS + t * BMT + tid;
      __builtin_nontemporal_store(v, pp);    // part is write-once/read-once
    }
  }
}

// ---------------- stage 2a: exact fp32 target scores -----------------------
__global__ void target_dot_kernel(const float* __restrict__ x,
                                  const float* __restrict__ W,
                                  const int* __restrict__ tgt,
                                  float* __restrict__ T) {
  int wave = threadIdx.x >> 6, lane = threadIdx.x & 63;
  int i = blockIdx.x * 4 + wave;                 // 1024 blocks * 4 waves = 4096
  int r = tgt[i];
  const float4* xp = (const float4*)(x + (size_t)i * DM + lane * 8);
  const float4* wp = (const float4*)(W + (size_t)r * DM + lane * 8);
  float4 a0 = xp[0], a1 = xp[1], b0 = wp[0], b1 = wp[1];
  float s = a0.x * b0.x + a0.y * b0.y + a0.z * b0.z + a0.w * b0.w
          + a1.x * b1.x + a1.y * b1.y + a1.z * b1.z + a1.w * b1.w;
  #pragma unroll
  for (int m = 32; m >= 1; m >>= 1) s += __shfl_xor(s, m, 64);
  if (lane == 0) T[i] = s;
}

// ---------------- stage 2b: reduce chunks, loss, total ---------------------
__global__ void reduce_loss_kernel(const float* __restrict__ part,
                                   const float* __restrict__ T,
                                   float* __restrict__ out) {
  __shared__ float red[256];
  int tid = threadIdx.x;
  int tok = blockIdx.x * 64 + (tid & 63);        // 64 blocks * 64 tokens
  int g = tid >> 6;
  float S = 0.f;
  #pragma unroll 5
  for (int cc = g; cc < NCHUNK; cc += 4) S += part[cc * TOKENS + tok];
  red[tid] = S;
  __syncthreads();
  if (tid < 64) {
    float Sa = red[tid] + red[64 + tid] + red[128 + tid] + red[192 + tid];
    float loss = __logf(Sa) - T[tok];            // = log s - t (max-free form)
    #pragma unroll
    for (int m = 32; m >= 1; m >>= 1) loss += __shfl_xor(loss, m, 64);
    if (tid == 0) atomicAdd(out, loss);
  }
}

extern "C" void kernel_launch(void* const* d_in, const int* in_sizes, int n_in,
                              void* d_out, int out_size, void* d_ws, size_t ws_size,
                              hipStream_t stream) {
  const float* x   = (const float*)d_in[0];
  const float* W   = (const float*)d_in[1];
  const int*   tgt = (const int*)d_in[2];
  float* out = (float*)d_out;

  unsigned short* xb   = (unsigned short*)((char*)d_ws + XBF_OFF);
  float*          part = (float*)((char*)d_ws + PART_OFF);
  float*          T    = (float*)((char*)d_ws + T_OFF);

  // allow 132 KB dynamic LDS (idempotent; host-side, safe under graph capture)
  hipFuncSetAttribute(reinterpret_cast<const void*>(gemm_sumexp_kernel),
                      hipFuncAttributeMaxDynamicSharedMemorySize, LDS_BYTES);

  cvt_x_kernel<<<TOKENS * DM / (256 * 4), 256, 0, stream>>>(x, xb, out);
  gemm_sumexp_kernel<<<NCHUNK, 1024, LDS_BYTES, stream>>>(W, xb, part);
  target_dot_kernel<<<TOKENS / 4, 256, 0, stream>>>(x, W, tgt, T);
  reduce_loss_kernel<<<TOKENS / 64, 256, 0, stream>>>(part, T, out);
}

// Round 4
// 918.504 us; speedup vs baseline: 1.4174x; 1.4174x over previous
//
#include <hip/hip_runtime.h>
#include <hip/hip_bf16.h>
#include <stdint.h>

// Problem constants
#define TOKENS 4096
#define DM     512
#define VOCAB  128000
#define BN     128                 // vocab rows per block (resident in LDS)
#define BMT    512                 // token tile (8 waves x 64 tokens)
#define NCHUNK (VOCAB / BN)        // 1000
#define NTILE  (TOKENS / BMT)      // 8

// ws layout (needs ~20.6 MB)
#define XBF_OFF  0
#define PART_OFF (TOKENS * DM * 2)                       // 4,194,304
#define T_OFF    (PART_OFF + NCHUNK * TOKENS * 4)        // +16,384,000
#define LDS_BYTES (BN * DM * 2)                          // 131072 (W only)

typedef __attribute__((ext_vector_type(8))) short short8;
typedef __attribute__((ext_vector_type(4))) float f32x4;
typedef __attribute__((ext_vector_type(16))) float f32x16;

__device__ __forceinline__ unsigned short f2bf(float f) {
  unsigned u;
  __builtin_memcpy(&u, &f, 4);
  u += 0x7fffu + ((u >> 16) & 1u);        // round-to-nearest-even
  return (unsigned short)(u >> 16);
}

// ---------------- stage 0: x fp32 -> bf16, zero the output scalar ----------
__global__ void cvt_x_kernel(const float* __restrict__ x,
                             unsigned short* __restrict__ xb,
                             float* __restrict__ out) {
  int i = (blockIdx.x * 256 + threadIdx.x) * 4;   // 2048 blocks * 256 * 4 = 2,097,152
  float4 v = *(const float4*)(x + i);
  ushort4 o;
  o.x = f2bf(v.x); o.y = f2bf(v.y); o.z = f2bf(v.z); o.w = f2bf(v.w);
  *(ushort4*)(xb + i) = o;
  if (blockIdx.x == 0 && threadIdx.x == 0) out[0] = 0.0f;
}

// ---------------- stage 1: W-chunk-resident GEMM + per-chunk sumexp --------
// R1 skeleton (512 thr, 8 waves, W resident in 128 KB LDS, X read from
// global/L2), upgraded to mfma_f32_32x32x16_bf16 with a full even/odd
// software pipeline on BOTH operands (prefetch distance ~1.5 clusters).
//
// W LDS layout: fragment-linear, rotated. Fragment unit = 16B (8 bf16) for
// (row 0..31 within rf, k-half 0..1) of K-16 cluster s. Group g = s*4+rf
// (128 groups x 1 KB). phys slot = g*64 + ((intra + g) & 63), where
// intra = kh*32 + row. A-read for (s, rf): lane l reads intra = l ->
// 64 consecutive (rotated) 16B slots of a contiguous 1 KB block: conflict-
// free. Rotation keeps the one-time store phase at ~8-way instead of 32-way.
//
// Wave tile: 128 vocab rows x 64 tokens = 4 rf (32-row) x 2 cf (32-token),
// acc[4][2] f32x16 = 128 regs, 8 MFMA per K-16 cluster, 32 clusters/tile.
__global__ __launch_bounds__(512, 2) void gemm_sumexp_kernel(
    const float* __restrict__ W, const unsigned short* __restrict__ Xb,
    float* __restrict__ part) {
  extern __shared__ char smem[];
  short8* Wl = (short8*)smem;                     // 8192 x 16B = 128 KB

  const int tid   = threadIdx.x;
  const int c     = blockIdx.x;
  const int lane  = tid & 63;
  const int w     = tid >> 6;       // wave 0..7 -> token group (64 tokens)
  const int tok32 = lane & 31;      // token/row within a 32-wide fragment
  const int half  = lane >> 5;      // k-half selector (k = half*8 + e)

  // ---- load W chunk fp32 -> bf16 -> LDS (fragment-linear rotated; once)
  {
    const float* Wg = W + (size_t)c * BN * DM;
    #pragma unroll
    for (int it = 0; it < 16; ++it) {
      int b  = it * 512 + tid;                // 0..8191 16B-blocks
      int n  = b >> 6;                        // W row 0..127
      int kb = b & 63;                        // 16B block within row
      const f32x4* p = (const f32x4*)(Wg + n * DM + kb * 8);
      f32x4 v0 = __builtin_nontemporal_load(p);      // W streamed: keep L2 for X
      f32x4 v1 = __builtin_nontemporal_load(p + 1);
      short8 s;
      s[0] = (short)f2bf(v0[0]); s[1] = (short)f2bf(v0[1]);
      s[2] = (short)f2bf(v0[2]); s[3] = (short)f2bf(v0[3]);
      s[4] = (short)f2bf(v1[0]); s[5] = (short)f2bf(v1[1]);
      s[6] = (short)f2bf(v1[2]); s[7] = (short)f2bf(v1[3]);
      int sE = kb >> 1, kh = kb & 1, rf = n >> 5, r0 = n & 31;
      int g = sE * 4 + rf;
      int intra = kh * 32 + r0;
      Wl[g * 64 + ((intra + g) & 63)] = s;
    }
  }
  __syncthreads();                  // only barrier in the kernel

  #pragma unroll 1
  for (int t = 0; t < NTILE; ++t) {
    f32x16 acc[4][2];
    #pragma unroll
    for (int i = 0; i < 4; ++i)
      #pragma unroll
      for (int j = 0; j < 2; ++j)
        acc[i][j] = (f32x16)(0.f);

    // B base: lane holds token (t*512 + w*64 + cf*32 + tok32),
    // k = s*16 + half*8 + e  -> 16B load at xbase + cf*32*DM + s*16
    const unsigned short* xbase =
        Xb + (size_t)(t * BMT + w * 64 + tok32) * DM + half * 8;

    short8 bfP[2], bfQ[2], afA[4], afB[4];

    // prologue: cluster 0 -> P/A, cluster 1 -> Q/B
    #pragma unroll
    for (int cf = 0; cf < 2; ++cf) {
      bfP[cf] = *(const short8*)(xbase + cf * 32 * DM + 0 * 16);
      bfQ[cf] = *(const short8*)(xbase + cf * 32 * DM + 1 * 16);
    }
    #pragma unroll
    for (int rf = 0; rf < 4; ++rf) {
      int g0 = 0 * 4 + rf, g1 = 1 * 4 + rf;
      afA[rf] = Wl[g0 * 64 + ((lane + g0) & 63)];
      afB[rf] = Wl[g1 * 64 + ((lane + g1) & 63)];
    }

    #pragma unroll 1
    for (int sp = 0; sp < 16; ++sp) {
      const int s0  = 2 * sp, s1 = 2 * sp + 1;
      const int sn0 = (s0 + 2) & 31;          // wrap: tail loads harmless
      const int sn1 = (s1 + 2) & 31;

      // ---- even phase: consume afA/bfP (cluster s0), prefetch s0+2
      __builtin_amdgcn_s_setprio(1);
      #pragma unroll
      for (int rf = 0; rf < 4; ++rf)
        #pragma unroll
        for (int cf = 0; cf < 2; ++cf)
          acc[rf][cf] = __builtin_amdgcn_mfma_f32_32x32x16_bf16(
              afA[rf], bfP[cf], acc[rf][cf], 0, 0, 0);
      __builtin_amdgcn_s_setprio(0);
      #pragma unroll
      for (int cf = 0; cf < 2; ++cf)
        bfP[cf] = *(const short8*)(xbase + cf * 32 * DM + sn0 * 16);
      #pragma unroll
      for (int rf = 0; rf < 4; ++rf) {
        int g = sn0 * 4 + rf;
        afA[rf] = Wl[g * 64 + ((lane + g) & 63)];
      }

      // ---- odd phase: consume afB/bfQ (cluster s1), prefetch s1+2
      __builtin_amdgcn_s_setprio(1);
      #pragma unroll
      for (int rf = 0; rf < 4; ++rf)
        #pragma unroll
        for (int cf = 0; cf < 2; ++cf)
          acc[rf][cf] = __builtin_amdgcn_mfma_f32_32x32x16_bf16(
              afB[rf], bfQ[cf], acc[rf][cf], 0, 0, 0);
      __builtin_amdgcn_s_setprio(0);
      #pragma unroll
      for (int cf = 0; cf < 2; ++cf)
        bfQ[cf] = *(const short8*)(xbase + cf * 32 * DM + sn1 * 16);
      #pragma unroll
      for (int rf = 0; rf < 4; ++rf) {
        int g = sn1 * 4 + rf;
        afB[rf] = Wl[g * 64 + ((lane + g) & 63)];
      }
    }

    // epilogue: 32x32 C/D layout: token = cf*32 + (lane&31),
    // vocab row = rf*32 + (reg&3) + 8*(reg>>2) + 4*half. Lanes l and l^32
    // hold complementary row halves of the SAME token -> one shfl_xor(32).
    #pragma unroll
    for (int cf = 0; cf < 2; ++cf) {
      float e = 0.f;
      #pragma unroll
      for (int rf = 0; rf < 4; ++rf) {
        #pragma unroll
        for (int r = 0; r < 16; ++r) e += __expf(acc[rf][cf][r]);
      }
      e += __shfl_xor(e, 32, 64);
      if (lane < 32) {
        float* pp = part + (size_t)c * TOKENS + t * BMT + w * 64 + cf * 32 + lane;
        __builtin_nontemporal_store(e, pp);   // part is write-once/read-once
      }
    }
  }
}

// ---------------- stage 2a: exact fp32 target scores -----------------------
__global__ void target_dot_kernel(const float* __restrict__ x,
                                  const float* __restrict__ W,
                                  const int* __restrict__ tgt,
                                  float* __restrict__ T) {
  int wave = threadIdx.x >> 6, lane = threadIdx.x & 63;
  int i = blockIdx.x * 4 + wave;                 // 1024 blocks * 4 waves = 4096
  int r = tgt[i];
  const float4* xp = (const float4*)(x + (size_t)i * DM + lane * 8);
  const float4* wp = (const float4*)(W + (size_t)r * DM + lane * 8);
  float4 a0 = xp[0], a1 = xp[1], b0 = wp[0], b1 = wp[1];
  float s = a0.x * b0.x + a0.y * b0.y + a0.z * b0.z + a0.w * b0.w
          + a1.x * b1.x + a1.y * b1.y + a1.z * b1.z + a1.w * b1.w;
  #pragma unroll
  for (int m = 32; m >= 1; m >>= 1) s += __shfl_xor(s, m, 64);
  if (lane == 0) T[i] = s;
}

// ---------------- stage 2b: reduce chunks, loss, total ---------------------
__global__ void reduce_loss_kernel(const float* __restrict__ part,
                                   const float* __restrict__ T,
                                   float* __restrict__ out) {
  __shared__ float red[256];
  int tid = threadIdx.x;
  int tok = blockIdx.x * 64 + (tid & 63);        // 64 blocks * 64 tokens
  int g = tid >> 6;
  float S = 0.f;
  #pragma unroll 5
  for (int cc = g; cc < NCHUNK; cc += 4) S += part[cc * TOKENS + tok];
  red[tid] = S;
  __syncthreads();
  if (tid < 64) {
    float Sa = red[tid] + red[64 + tid] + red[128 + tid] + red[192 + tid];
    float loss = __logf(Sa) - T[tok];            // = log s - t (max-free form)
    #pragma unroll
    for (int m = 32; m >= 1; m >>= 1) loss += __shfl_xor(loss, m, 64);
    if (tid == 0) atomicAdd(out, loss);
  }
}

extern "C" void kernel_launch(void* const* d_in, const int* in_sizes, int n_in,
                              void* d_out, int out_size, void* d_ws, size_t ws_size,
                              hipStream_t stream) {
  const float* x   = (const float*)d_in[0];
  const float* W   = (const float*)d_in[1];
  const int*   tgt = (const int*)d_in[2];
  float* out = (float*)d_out;

  unsigned short* xb   = (unsigned short*)((char*)d_ws + XBF_OFF);
  float*          part = (float*)((char*)d_ws + PART_OFF);
  float*          T    = (float*)((char*)d_ws + T_OFF);

  // allow 128 KB dynamic LDS (idempotent; host-side, safe under graph capture)
  hipFuncSetAttribute(reinterpret_cast<const void*>(gemm_sumexp_kernel),
                      hipFuncAttributeMaxDynamicSharedMemorySize, LDS_BYTES);

  cvt_x_kernel<<<TOKENS * DM / (256 * 4), 256, 0, stream>>>(x, xb, out);
  gemm_sumexp_kernel<<<NCHUNK, 512, LDS_BYTES, stream>>>(W, xb, part);
  target_dot_kernel<<<TOKENS / 4, 256, 0, stream>>>(x, W, tgt, T);
  reduce_loss_kernel<<<TOKENS / 64, 256, 0, stream>>>(part, T, out);
}